// Round 12
// baseline (212.469 us; speedup 1.0000x reference)
//
#include <hip/hip_runtime.h>

typedef __bf16 bf16;
typedef __bf16 bf16x8 __attribute__((ext_vector_type(8)));
typedef __bf16 bf16x4 __attribute__((ext_vector_type(4)));
typedef float f32x4 __attribute__((ext_vector_type(4)));
typedef float f32x16 __attribute__((ext_vector_type(16)));
typedef float fx2 __attribute__((ext_vector_type(2)));

#define DEV static __device__ __forceinline__

constexpr int BB = 2, SS = 2048, DM = 1024, NH = 16, HD = 64;
constexpr int MTOT = BB * SS;  // 4096
constexpr float LOG2E = 1.4426950408889634f;

// ---- workspace layout (bytes) ----
constexpr size_t OFF_XB   = 0;                                  // bf16 [4096][1024]
constexpr size_t OFF_WQKV = OFF_XB   + (size_t)MTOT * DM * 2;   // bf16 [3072][1024]
constexpr size_t OFF_WO   = OFF_WQKV + (size_t)3 * DM * DM * 2; // bf16 [1024][1024]
constexpr size_t OFF_TAB  = OFF_WO   + (size_t)DM * DM * 2;     // fx2  [2048][32]
constexpr size_t OFF_Q    = OFF_TAB  + (size_t)SS * (HD/2) * 8; // bf16 (B,H,S,d)
constexpr size_t OFF_K    = OFF_Q    + (size_t)MTOT * DM * 2;
constexpr size_t OFF_VT   = OFF_K    + (size_t)MTOT * DM * 2;   // bf16 (B,H,d,S)
constexpr size_t OFF_AO   = OFF_VT   + (size_t)MTOT * DM * 2;   // bf16 [4096][1024]

typedef const __attribute__((address_space(1))) void gas_void;
typedef __attribute__((address_space(3))) void las_void;

DEV void gload16(const bf16* g, bf16* l) {
  __builtin_amdgcn_global_load_lds((gas_void*)g, (las_void*)l, 16, 0, 0);
}

DEV f32x4 mfma16(bf16x8 a, bf16x8 b, f32x4 c) {
  return __builtin_amdgcn_mfma_f32_16x16x32_bf16(a, b, c, 0, 0, 0);
}

DEV f32x16 mfma32(bf16x8 a, bf16x8 b, f32x16 c) {
  return __builtin_amdgcn_mfma_f32_32x32x16_bf16(a, b, c, 0, 0, 0);
}

DEV unsigned pack2(float a, float b) {
  union { bf16 h[2]; unsigned u; } cv;
  cv.h[0] = (bf16)a; cv.h[1] = (bf16)b;
  return cv.u;
}

// ---------------- prep: fp32 -> bf16 casts + RoPE table ----------------
__global__ void prep_kernel(const float* __restrict__ x, const float* __restrict__ wq,
    const float* __restrict__ wk, const float* __restrict__ wv, const float* __restrict__ wo,
    const int* __restrict__ pos, bf16* __restrict__ xb, bf16* __restrict__ wqkv,
    bf16* __restrict__ wob, fx2* __restrict__ tab) {
  const int NX4 = MTOT * DM / 4;     // 1048576
  const int NW4 = DM * DM / 4;       // 262144 = 2^18
  const int TOTC = NX4 + 4 * NW4;    // 2097152
  const int NTAB = SS * (HD / 2);    // 65536
  const int total = TOTC + NTAB;
  for (int i = blockIdx.x * blockDim.x + threadIdx.x; i < total; i += gridDim.x * blockDim.x) {
    if (i < TOTC) {
      const float* src; bf16* dst; int off;
      if (i < NX4) { src = x; dst = xb; off = i; }
      else {
        int i2 = i - NX4; int which = i2 >> 18; off = i2 & (NW4 - 1);
        src = which == 0 ? wq : which == 1 ? wk : which == 2 ? wv : wo;
        dst = which == 0 ? wqkv : which == 1 ? wqkv + DM * DM : which == 2 ? wqkv + 2 * DM * DM : wob;
      }
      float4 v = ((const float4*)src)[off];
      bf16x4 o4 = { (bf16)v.x, (bf16)v.y, (bf16)v.z, (bf16)v.w };
      ((bf16x4*)dst)[off] = o4;
    } else {
      int e = i - TOTC;
      int s = e >> 5, p = e & 31;
      float invf = __builtin_exp2f(-(float)p * (13.287712379549449f / 32.0f));
      float ang = (float)pos[s] * invf;
      fx2 cs; cs.x = cosf(ang); cs.y = sinf(ang);
      tab[e] = cs;
    }
  }
}

// ---------------- 128x128 bf16 GEMM mainloop (C[m,n] = sum_k A[m,k]*B[n,k]) ----------------
DEV void gemm_bt_128(const bf16* __restrict__ A, const bf16* __restrict__ Bw,
                     int rowA0, int rowB0, f32x4 (&acc)[4][4]) {
  __shared__ __align__(16) bf16 lA[128 * 32];
  __shared__ __align__(16) bf16 lB[128 * 32];
  const int t = threadIdx.x, w = t >> 6, lane = t & 63;
  const int wr = w >> 1, wc = w & 1, g = lane >> 4, c = lane & 15;
#pragma unroll
  for (int mi = 0; mi < 4; mi++)
#pragma unroll
    for (int ni = 0; ni < 4; ni++) acc[mi][ni] = (f32x4){0.f, 0.f, 0.f, 0.f};
  const bf16* ga = A + (size_t)(rowA0 + (t >> 2)) * DM + (t & 3) * 8;
  const bf16* gb = Bw + (size_t)(rowB0 + (t >> 2)) * DM + (t & 3) * 8;
  bf16* la = lA + w * 512;
  bf16* lb = lB + w * 512;
  const int arow = wr * 64 + c, brow = wc * 64 + c;
  for (int k0 = 0; k0 < DM; k0 += 32) {
    gload16(ga + k0,            la);
    gload16(ga + k0 + 64 * DM,  la + 2048);
    gload16(gb + k0,            lb);
    gload16(gb + k0 + 64 * DM,  lb + 2048);
    __syncthreads();
    bf16x8 af[4], bf_[4];
#pragma unroll
    for (int mi = 0; mi < 4; mi++) af[mi]  = *(const bf16x8*)(lA + (arow + mi * 16) * 32 + g * 8);
#pragma unroll
    for (int ni = 0; ni < 4; ni++) bf_[ni] = *(const bf16x8*)(lB + (brow + ni * 16) * 32 + g * 8);
#pragma unroll
    for (int mi = 0; mi < 4; mi++)
#pragma unroll
      for (int ni = 0; ni < 4; ni++)
        acc[mi][ni] = mfma16(af[mi], bf_[ni], acc[mi][ni]);
    __syncthreads();
  }
}

// ---------------- QKV projection + RoPE epilogue ----------------
__global__ __launch_bounds__(256, 2) void qkv_kernel(const bf16* __restrict__ xb,
    const bf16* __restrict__ wqkv, const fx2* __restrict__ tab,
    bf16* __restrict__ Qb, bf16* __restrict__ Kb, bf16* __restrict__ VTb) {
  f32x4 acc[4][4];
  const int rowA0 = blockIdx.y * 128, rowB0 = blockIdx.x * 128;
  gemm_bt_128(xb, wqkv, rowA0, rowB0, acc);
  const int t = threadIdx.x, w = t >> 6, lane = t & 63;
  const int wr = w >> 1, wc = w & 1, g = lane >> 4, c = lane & 15;
  const int which = rowB0 >> 10;
#pragma unroll
  for (int mi = 0; mi < 4; mi++)
#pragma unroll
    for (int ni = 0; ni < 4; ni++) {
      const int ncol = rowB0 + wc * 64 + ni * 16 + c;
      const int nn = ncol & (DM - 1), h = nn >> 6, dd = nn & 63;
#pragma unroll
      for (int j = 0; j < 4; j++) {
        const int mrow = rowA0 + wr * 64 + mi * 16 + 4 * g + j;
        const int b = mrow >> 11, s = mrow & (SS - 1);
        float v = acc[mi][ni][j];
        if (which < 2) {
          float partner = __shfl_xor(v, 1);
          fx2 cs = tab[s * 32 + (dd >> 1)];
          v = v * cs.x + ((dd & 1) ? partner : -partner) * cs.y;
          bf16* dst = which == 0 ? Qb : Kb;
          dst[((size_t)((b * NH + h) * SS + s)) * HD + dd] = (bf16)v;
        } else {
          VTb[((size_t)((b * NH + h) * HD + dd)) * SS + s] = (bf16)v;
        }
      }
    }
}

// ---------------- flash attention (causal), cooperative 2-wave blocks ----------------
// 512 blocks (16 p x 32 bh) x 128 thr. Block covers 128 q-rows: wave w owns
// [qbase + w*64, +64) as two 32-row subs (R11's verified swapped-operand body).
// K AND V^T (64x64 each) staged ONCE per block per tile into shared LDS dbuf
// (T3 minimal 2-phase recipe: stage next -> compute current -> vmcnt(0) -> bar).
// Arithmetic intensity 4x R11: 16KB serves 128 q-rows. Causal pairing p / 15-p
// -> uniform 34 tiles/block. XOR-swizzled source staging + swizzled reads (#21).
__global__ __launch_bounds__(128, 1) void attn_kernel(const bf16* __restrict__ Q,
    const bf16* __restrict__ K, const bf16* __restrict__ VT, bf16* __restrict__ AO) {
  __shared__ __align__(16) unsigned char smem[32768];   // dbuf: 2 x (K 8KB + V 8KB)
  const int flat = blockIdx.x;                   // 0..511
  const int flat2 = (flat & 7) * 64 + (flat >> 3);
  const int bh = flat2 >> 4;                     // 0..31 (4 per XCD)
  const int p = flat2 & 15;                      // pair index 0..15
  const int w = threadIdx.x >> 6;                // wave 0/1
  const int lane = threadIdx.x & 63;
  const int q31 = lane & 31, hi = lane >> 5;
  const bf16* Qp = Q + (size_t)bh * SS * HD;
  const bf16* Kp = K + (size_t)bh * SS * HD;
  const bf16* Vp = VT + (size_t)bh * HD * SS;
  const float SCL = 0.125f * LOG2E;

  // cooperative stage: wave w covers rows [w*32, w*32+32) of both K and V^T
  // tiles. Linear LDS dest + inverse-swizzled global source (rule #21):
  // physical[row][c16] = logical[row][c16 ^ (row&7)]; lane L: row_local=L>>3.
  const int srow = (lane >> 3), scol = ((lane & 7) ^ (lane >> 3)) * 8;
  auto stageKV = [&](int k0, unsigned koff) {
    const bf16* ksrc = Kp + (size_t)(k0 + w * 32 + srow) * HD + scol;
    bf16* kdst = (bf16*)(smem + koff) + (w * 32) * 64;
#pragma unroll
    for (int i = 0; i < 4; i++)
      gload16(ksrc + i * 8 * HD, kdst + i * 512);
    const bf16* vsrc = Vp + (size_t)(w * 32 + srow) * SS + k0 + scol;
    bf16* vdst = (bf16*)(smem + koff + 8192) + (w * 32) * 64;
#pragma unroll
    for (int i = 0; i < 4; i++)
      gload16(vsrc + i * 8 * SS, vdst + i * 512);
  };

  // online softmax + P->B-frag pack for one 32-row sub (R11 verified body)
  auto sm_pack = [&](f32x16& s0, f32x16& s1, float& m_r, float& lsum,
                     f32x16& o0, f32x16& o1, bf16x8 (&pf)[4]) {
    float a[16];
#pragma unroll
    for (int r = 0; r < 16; r++) a[r] = fmaxf(s0[r], s1[r]);
#pragma unroll
    for (int d = 8; d > 0; d >>= 1)
#pragma unroll
      for (int r = 0; r < d; r++) a[r] = fmaxf(a[r], a[r + d]);
    const float pm = fmaxf(a[0], __shfl_xor(a[0], 32));
    if (__any(pm > m_r + 8.0f)) {                // T13 defer-max, THR=8
      const float mnew = fmaxf(m_r, pm);
      const float alpha = __builtin_exp2f(m_r - mnew);
      lsum *= alpha;
#pragma unroll
      for (int e = 0; e < 16; e++) { o0[e] *= alpha; o1[e] *= alpha; }
      m_r = mnew;
    }
    float b[16];
#pragma unroll
    for (int r = 0; r < 16; r++) {
      s0[r] = __builtin_exp2f(s0[r] - m_r);
      s1[r] = __builtin_exp2f(s1[r] - m_r);
      b[r] = s0[r] + s1[r];
    }
#pragma unroll
    for (int d = 8; d > 0; d >>= 1)
#pragma unroll
      for (int r = 0; r < d; r++) b[r] += b[r + d];
    lsum += b[0] + __shfl_xor(b[0], 32);
#pragma unroll
    for (int ks = 0; ks < 4; ks++) {
      const int rb = 8 * (ks & 1);
      float va0, va1, va2, va3, vb0, vb1, vb2, vb3;
      if (ks < 2) {
        va0 = s0[rb]; va1 = s0[rb + 1]; va2 = s0[rb + 2]; va3 = s0[rb + 3];
        vb0 = s0[rb + 4]; vb1 = s0[rb + 5]; vb2 = s0[rb + 6]; vb3 = s0[rb + 7];
      } else {
        va0 = s1[rb]; va1 = s1[rb + 1]; va2 = s1[rb + 2]; va3 = s1[rb + 3];
        vb0 = s1[rb + 4]; vb1 = s1[rb + 5]; vb2 = s1[rb + 6]; vb3 = s1[rb + 7];
      }
      const unsigned a01 = pack2(va0, va1), a23 = pack2(va2, va3);
      const unsigned b01 = pack2(vb0, vb1), b23 = pack2(vb2, vb3);
      const unsigned z1 = (unsigned)__shfl_xor((int)(hi ? a01 : b01), 32);
      const unsigned z2 = (unsigned)__shfl_xor((int)(hi ? a23 : b23), 32);
      union { unsigned u[4]; bf16x8 v; } cv;
      cv.u[0] = hi ? z1 : a01;
      cv.u[1] = hi ? z2 : a23;
      cv.u[2] = hi ? b01 : z1;
      cv.u[3] = hi ? b23 : z2;
      pf[ks] = cv.v;
    }
  };

  auto run_phase = [&](int qbase, int nt) {
    const int qA = qbase + w * 64;               // sub A rows [qA, qA+32)
    const int qB = qA + 32;                      // sub B rows [qB, qB+32)
    // Q frags (B-operand), scaled into exp2 domain
    bf16x8 qbA[4], qbB[4];
#pragma unroll
    for (int ds = 0; ds < 4; ds++) {
      bf16x8 xa = *(const bf16x8*)(Qp + (size_t)(qA + q31) * HD + ds * 16 + hi * 8);
      bf16x8 xb2 = *(const bf16x8*)(Qp + (size_t)(qB + q31) * HD + ds * 16 + hi * 8);
#pragma unroll
      for (int e = 0; e < 8; e++) {
        xa[e] = (bf16)((float)xa[e] * SCL);
        xb2[e] = (bf16)((float)xb2[e] * SCL);
      }
      qbA[ds] = xa; qbB[ds] = xb2;
    }
    float mA = -3.0e38f, lA = 0.f, mB = -3.0e38f, lB = 0.f;
    f32x16 oA0, oA1, oB0, oB1;
#pragma unroll
    for (int e = 0; e < 16; e++) { oA0[e] = 0.f; oA1[e] = 0.f; oB0[e] = 0.f; oB1[e] = 0.f; }

    stageKV(0, 0);
    asm volatile("s_waitcnt vmcnt(0)" ::: "memory");
    __syncthreads();
    unsigned cur = 0;
    for (int tv = 0; tv < nt; ++tv) {
      const int k0 = tv * 64;
      if (tv + 1 < nt) stageKV(k0 + 64, (cur ^ 1) * 16384);
      const bool actA = (k0 < qA + 32);
      const bool actB = (k0 < qB + 32);
      const unsigned kb0 = cur * 16384;
      const unsigned sw = (unsigned)(q31 & 7) << 4;
      // ---- QK^T both subs (K frags read once) ----
      f32x16 sA0, sA1, sB0, sB1;
#pragma unroll
      for (int e = 0; e < 16; e++) { sA0[e] = 0.f; sA1[e] = 0.f; sB0[e] = 0.f; sB1[e] = 0.f; }
#pragma unroll
      for (int ds = 0; ds < 4; ds++) {
        const unsigned co = (((unsigned)(ds * 2 + hi)) << 4) ^ sw;
        bf16x8 kf0 = *(const bf16x8*)(smem + kb0 + (unsigned)q31 * 128 + co);
        bf16x8 kf1 = *(const bf16x8*)(smem + kb0 + (unsigned)(32 + q31) * 128 + co);
        if (actA) { sA0 = mfma32(kf0, qbA[ds], sA0); sA1 = mfma32(kf1, qbA[ds], sA1); }
        if (actB) { sB0 = mfma32(kf0, qbB[ds], sB0); sB1 = mfma32(kf1, qbB[ds], sB1); }
      }
      // ---- causal masks ----
      if (actA && (k0 + 63 > qA)) {
        const int qg = qA + q31;
#pragma unroll
        for (int r = 0; r < 16; r++) {
          const int kg = k0 + (r & 3) + 8 * (r >> 2) + 4 * hi;
          if (kg > qg)      sA0[r] = -1.0e30f;
          if (kg + 32 > qg) sA1[r] = -1.0e30f;
        }
      }
      if (actB && (k0 + 63 > qB)) {
        const int qg = qB + q31;
#pragma unroll
        for (int r = 0; r < 16; r++) {
          const int kg = k0 + (r & 3) + 8 * (r >> 2) + 4 * hi;
          if (kg > qg)      sB0[r] = -1.0e30f;
          if (kg + 32 > qg) sB1[r] = -1.0e30f;
        }
      }
      // ---- softmax + pack per sub ----
      bf16x8 pfA[4], pfB[4];
      if (actA) sm_pack(sA0, sA1, mA, lA, oA0, oA1, pfA);
      if (actB) sm_pack(sB0, sB1, mB, lB, oB0, oB1, pfB);
      // ---- V frags from LDS (swizzled read; conflict-free distinct rows) ----
      bf16x8 vf[2][4];
#pragma unroll
      for (int dt = 0; dt < 2; dt++)
#pragma unroll
        for (int ks = 0; ks < 4; ks++) {
          const unsigned row = (unsigned)(dt * 32 + q31);
          const unsigned co = (((unsigned)(ks * 2 + hi)) << 4) ^ sw;
          vf[dt][ks] = *(const bf16x8*)(smem + kb0 + 8192 + row * 128 + co);
        }
      // ---- PV per sub ----
      if (actA) {
#pragma unroll
        for (int ks = 0; ks < 4; ks++) {
          oA0 = mfma32(vf[0][ks], pfA[ks], oA0);
          oA1 = mfma32(vf[1][ks], pfA[ks], oA1);
        }
      }
      if (actB) {
#pragma unroll
        for (int ks = 0; ks < 4; ks++) {
          oB0 = mfma32(vf[0][ks], pfB[ks], oB0);
          oB1 = mfma32(vf[1][ks], pfB[ks], oB1);
        }
      }
      asm volatile("s_waitcnt vmcnt(0)" ::: "memory");
      __syncthreads();
      cur ^= 1;
    }
    // ---- epilogue: in-lane normalize, store both subs ----
    const int b = bh >> 4, h = bh & 15;
    auto store_sub = [&](f32x16& o0, f32x16& o1, float lsum, int qX) {
      const float inv = 1.0f / lsum;
      const size_t rowb = ((size_t)(b * SS + qX + q31)) * DM + h * HD;
#pragma unroll
      for (int g2 = 0; g2 < 4; g2++) {
        bf16x4 w0, w1;
#pragma unroll
        for (int j = 0; j < 4; j++) {
          w0[j] = (bf16)(o0[4 * g2 + j] * inv);
          w1[j] = (bf16)(o1[4 * g2 + j] * inv);
        }
        *(bf16x4*)(AO + rowb +      8 * g2 + 4 * hi) = w0;
        *(bf16x4*)(AO + rowb + 32 + 8 * g2 + 4 * hi) = w1;
      }
    };
    store_sub(oA0, oA1, lA, qA);
    store_sub(oB0, oB1, lB, qB);
    __syncthreads();   // phase boundary: all reads done before next phase stages
  };

  run_phase(p * 128, 2 * p + 2);
  run_phase((15 - p) * 128, 32 - 2 * p);
}

// ---------------- output projection -> fp32 d_out ----------------
__global__ __launch_bounds__(256, 2) void oproj_kernel(const bf16* __restrict__ AO,
    const bf16* __restrict__ wob, float* __restrict__ out) {
  f32x4 acc[4][4];
  const int rowA0 = blockIdx.y * 128, rowB0 = blockIdx.x * 128;
  gemm_bt_128(AO, wob, rowA0, rowB0, acc);
  const int t = threadIdx.x, w = t >> 6, lane = t & 63;
  const int wr = w >> 1, wc = w & 1, g = lane >> 4, c = lane & 15;
#pragma unroll
  for (int mi = 0; mi < 4; mi++)
#pragma unroll
    for (int ni = 0; ni < 4; ni++) {
      const int ncol = rowB0 + wc * 64 + ni * 16 + c;
#pragma unroll
      for (int j = 0; j < 4; j++) {
        const int mrow = rowA0 + wr * 64 + mi * 16 + 4 * g + j;
        out[(size_t)mrow * DM + ncol] = acc[mi][ni][j];
      }
    }
}

extern "C" void kernel_launch(void* const* d_in, const int* in_sizes, int n_in,
                              void* d_out, int out_size, void* d_ws, size_t ws_size,
                              hipStream_t stream) {
  const float* x  = (const float*)d_in[0];
  const float* wq = (const float*)d_in[1];
  const float* wk = (const float*)d_in[2];
  const float* wv = (const float*)d_in[3];
  const float* wo = (const float*)d_in[4];
  const int*   pos = (const int*)d_in[5];
  char* ws = (char*)d_ws;
  bf16* xb   = (bf16*)(ws + OFF_XB);
  bf16* wqkv = (bf16*)(ws + OFF_WQKV);
  bf16* wob  = (bf16*)(ws + OFF_WO);
  fx2*  tab  = (fx2*)(ws + OFF_TAB);
  bf16* Qb   = (bf16*)(ws + OFF_Q);
  bf16* Kb   = (bf16*)(ws + OFF_K);
  bf16* VTb  = (bf16*)(ws + OFF_VT);
  bf16* AOb  = (bf16*)(ws + OFF_AO);

  hipLaunchKernelGGL(prep_kernel, dim3(2048), dim3(256), 0, stream,
                     x, wq, wk, wv, wo, pos, xb, wqkv, wob, tab);
  hipLaunchKernelGGL(qkv_kernel, dim3(24, 32), dim3(256), 0, stream,
                     xb, wqkv, tab, Qb, Kb, VTb);
  hipLaunchKernelGGL(attn_kernel, dim3(512), dim3(128), 0, stream,
                     Qb, Kb, VTb, AOb);
  hipLaunchKernelGGL(oproj_kernel, dim3(8, 32), dim3(256), 0, stream,
                     AOb, wob, (float*)d_out);
}

// Round 14
// 129.766 us; speedup vs baseline: 1.6373x; 1.6373x over previous
//
#include <hip/hip_runtime.h>

typedef __bf16 bf16;
typedef __bf16 bf16x8 __attribute__((ext_vector_type(8)));
typedef __bf16 bf16x4 __attribute__((ext_vector_type(4)));
typedef float f32x4 __attribute__((ext_vector_type(4)));
typedef float f32x16 __attribute__((ext_vector_type(16)));
typedef float fx2 __attribute__((ext_vector_type(2)));

#define DEV static __device__ __forceinline__

constexpr int BB = 2, SS = 2048, DM = 1024, NH = 16, HD = 64;
constexpr int MTOT = BB * SS;  // 4096
constexpr float LOG2E = 1.4426950408889634f;

// ---- workspace layout (bytes) ----
constexpr size_t OFF_XB   = 0;                                  // bf16 [4096][1024]
constexpr size_t OFF_WQKV = OFF_XB   + (size_t)MTOT * DM * 2;   // bf16 [3072][1024]
constexpr size_t OFF_WO   = OFF_WQKV + (size_t)3 * DM * DM * 2; // bf16 [1024][1024]
constexpr size_t OFF_TAB  = OFF_WO   + (size_t)DM * DM * 2;     // fx2  [2048][32]
constexpr size_t OFF_Q    = OFF_TAB  + (size_t)SS * (HD/2) * 8; // bf16 (B,H,S,d)
constexpr size_t OFF_K    = OFF_Q    + (size_t)MTOT * DM * 2;
constexpr size_t OFF_VF   = OFF_K    + (size_t)MTOT * DM * 2;   // bf16 pre-fragmented V
constexpr size_t OFF_AO   = OFF_VF   + (size_t)MTOT * DM * 2;   // bf16 [4096][1024]

typedef const __attribute__((address_space(1))) void gas_void;
typedef __attribute__((address_space(3))) void las_void;

DEV void gload16(const bf16* g, bf16* l) {
  __builtin_amdgcn_global_load_lds((gas_void*)g, (las_void*)l, 16, 0, 0);
}

DEV f32x4 mfma16(bf16x8 a, bf16x8 b, f32x4 c) {
  return __builtin_amdgcn_mfma_f32_16x16x32_bf16(a, b, c, 0, 0, 0);
}

DEV f32x16 mfma32(bf16x8 a, bf16x8 b, f32x16 c) {
  return __builtin_amdgcn_mfma_f32_32x32x16_bf16(a, b, c, 0, 0, 0);
}

DEV unsigned pack2(float a, float b) {
  union { bf16 h[2]; unsigned u; } cv;
  cv.h[0] = (bf16)a; cv.h[1] = (bf16)b;
  return cv.u;
}

// ---------------- prep: fp32 -> bf16 casts + RoPE table ----------------
__global__ void prep_kernel(const float* __restrict__ x, const float* __restrict__ wq,
    const float* __restrict__ wk, const float* __restrict__ wv, const float* __restrict__ wo,
    const int* __restrict__ pos, bf16* __restrict__ xb, bf16* __restrict__ wqkv,
    bf16* __restrict__ wob, fx2* __restrict__ tab) {
  const int NX4 = MTOT * DM / 4;     // 1048576
  const int NW4 = DM * DM / 4;       // 262144 = 2^18
  const int TOTC = NX4 + 4 * NW4;    // 2097152
  const int NTAB = SS * (HD / 2);    // 65536
  const int total = TOTC + NTAB;
  for (int i = blockIdx.x * blockDim.x + threadIdx.x; i < total; i += gridDim.x * blockDim.x) {
    if (i < TOTC) {
      const float* src; bf16* dst; int off;
      if (i < NX4) { src = x; dst = xb; off = i; }
      else {
        int i2 = i - NX4; int which = i2 >> 18; off = i2 & (NW4 - 1);
        src = which == 0 ? wq : which == 1 ? wk : which == 2 ? wv : wo;
        dst = which == 0 ? wqkv : which == 1 ? wqkv + DM * DM : which == 2 ? wqkv + 2 * DM * DM : wob;
      }
      float4 v = ((const float4*)src)[off];
      bf16x4 o4 = { (bf16)v.x, (bf16)v.y, (bf16)v.z, (bf16)v.w };
      ((bf16x4*)dst)[off] = o4;
    } else {
      int e = i - TOTC;
      int s = e >> 5, p = e & 31;
      float invf = __builtin_exp2f(-(float)p * (13.287712379549449f / 32.0f));
      float ang = (float)pos[s] * invf;
      fx2 cs; cs.x = cosf(ang); cs.y = sinf(ang);
      tab[e] = cs;
    }
  }
}

// ---------------- 128x128 bf16 GEMM mainloop (C[m,n] = sum_k A[m,k]*B[n,k]) ----------------
DEV void gemm_bt_128(const bf16* __restrict__ A, const bf16* __restrict__ Bw,
                     int rowA0, int rowB0, f32x4 (&acc)[4][4]) {
  __shared__ __align__(16) bf16 lA[128 * 32];
  __shared__ __align__(16) bf16 lB[128 * 32];
  const int t = threadIdx.x, w = t >> 6, lane = t & 63;
  const int wr = w >> 1, wc = w & 1, g = lane >> 4, c = lane & 15;
#pragma unroll
  for (int mi = 0; mi < 4; mi++)
#pragma unroll
    for (int ni = 0; ni < 4; ni++) acc[mi][ni] = (f32x4){0.f, 0.f, 0.f, 0.f};
  const bf16* ga = A + (size_t)(rowA0 + (t >> 2)) * DM + (t & 3) * 8;
  const bf16* gb = Bw + (size_t)(rowB0 + (t >> 2)) * DM + (t & 3) * 8;
  bf16* la = lA + w * 512;
  bf16* lb = lB + w * 512;
  const int arow = wr * 64 + c, brow = wc * 64 + c;
  for (int k0 = 0; k0 < DM; k0 += 32) {
    gload16(ga + k0,            la);
    gload16(ga + k0 + 64 * DM,  la + 2048);
    gload16(gb + k0,            lb);
    gload16(gb + k0 + 64 * DM,  lb + 2048);
    __syncthreads();
    bf16x8 af[4], bf_[4];
#pragma unroll
    for (int mi = 0; mi < 4; mi++) af[mi]  = *(const bf16x8*)(lA + (arow + mi * 16) * 32 + g * 8);
#pragma unroll
    for (int ni = 0; ni < 4; ni++) bf_[ni] = *(const bf16x8*)(lB + (brow + ni * 16) * 32 + g * 8);
#pragma unroll
    for (int mi = 0; mi < 4; mi++)
#pragma unroll
      for (int ni = 0; ni < 4; ni++)
        acc[mi][ni] = mfma16(af[mi], bf_[ni], acc[mi][ni]);
    __syncthreads();
  }
}

// ---------------- QKV projection + RoPE epilogue ----------------
// V is written in the PRE-FRAGMENTED layout VF[bh][t][dt][ks][lane][e]:
//   for key index s and head-dim d:  t=s>>6, ks=(s>>4)&3, hi=(s>>3)&1, e=s&7,
//   dt=d>>5, lane=(d&31)+32*hi.  attn's PV A-frag load is then one contiguous
//   1KB load per (dt,ks) instead of 32 scattered 32B transactions.
__global__ __launch_bounds__(256, 2) void qkv_kernel(const bf16* __restrict__ xb,
    const bf16* __restrict__ wqkv, const fx2* __restrict__ tab,
    bf16* __restrict__ Qb, bf16* __restrict__ Kb, bf16* __restrict__ VFb) {
  f32x4 acc[4][4];
  const int rowA0 = blockIdx.y * 128, rowB0 = blockIdx.x * 128;
  gemm_bt_128(xb, wqkv, rowA0, rowB0, acc);
  const int t = threadIdx.x, w = t >> 6, lane = t & 63;
  const int wr = w >> 1, wc = w & 1, g = lane >> 4, c = lane & 15;
  const int which = rowB0 >> 10;
#pragma unroll
  for (int mi = 0; mi < 4; mi++)
#pragma unroll
    for (int ni = 0; ni < 4; ni++) {
      const int ncol = rowB0 + wc * 64 + ni * 16 + c;
      const int nn = ncol & (DM - 1), h = nn >> 6, dd = nn & 63;
#pragma unroll
      for (int j = 0; j < 4; j++) {
        const int mrow = rowA0 + wr * 64 + mi * 16 + 4 * g + j;
        const int b = mrow >> 11, s = mrow & (SS - 1);
        float v = acc[mi][ni][j];
        if (which < 2) {
          float partner = __shfl_xor(v, 1);
          fx2 cs = tab[s * 32 + (dd >> 1)];
          v = v * cs.x + ((dd & 1) ? partner : -partner) * cs.y;
          bf16* dst = which == 0 ? Qb : Kb;
          dst[((size_t)((b * NH + h) * SS + s)) * HD + dd] = (bf16)v;
        } else {
          // ts = s & 63 = mi*16 + 4g + j  ->  ks=mi, hi=g>>1, e=(4g+j)&7
          // t2 must be the WITHIN-SEQUENCE tile index: mask off the batch bit
          const int t2 = ((rowA0 & (SS - 1)) >> 6) + wr;    // s>>6  (R13 bugfix)
          const int e2 = (4 * g + j) & 7;
          const int lane2 = (dd & 31) + 32 * (g >> 1);
          VFb[(((((size_t)(b * NH + h) * 32 + t2) * 2 + (dd >> 5)) * 4 + mi) * 64 + lane2) * 8 + e2] = (bf16)v;
        }
      }
    }
}

// ---------------- flash attention (causal), swapped 32x32, 2-wave split-k ----------------
// R11 structure (best, 58us) + pre-fragmented V: each V fragment is one
// CONTIGUOUS 1KB load (was 32x 32B scattered transactions at stride 4KB).
// 1024 blocks x 128 thr. Paired chunks p & 63-p (33 tiles/block, uniform).
// Wave w handles tiles tv = w, w+2, ...: K dbuf half, m/l/O, vmcnt discipline
// all WAVE-PRIVATE -> zero barriers in the k-loop. End-of-chunk LDS merge.
__global__ __launch_bounds__(128, 2) void attn_kernel(const bf16* __restrict__ Q,
    const bf16* __restrict__ K, const bf16* __restrict__ VF, bf16* __restrict__ AO) {
  __shared__ __align__(16) unsigned char smem[32768];
  const int flat = blockIdx.x;                       // 0..1023
  const int flat2 = (flat & 7) * 128 + (flat >> 3);  // XCD-contiguous
  const int bh = flat2 >> 5;                         // 0..31 (4 per XCD)
  const int p = flat2 & 31;                          // pair index
  const int w = threadIdx.x >> 6;                    // wave 0/1
  const int lane = threadIdx.x & 63;
  const int q31 = lane & 31, hi = lane >> 5;
  const bf16* Qp = Q + (size_t)bh * SS * HD;
  const bf16* Kp = K + (size_t)bh * SS * HD;
  const bf16* VFp = VF + (size_t)bh * SS * HD;       // 131072 bf16 per bh
  const float SCL = 0.125f * LOG2E;                  // exp2-domain scale
  const unsigned wbase = (unsigned)w * 16384;
  float* Om = (float*)(smem + 16384);                // [64][32] f32 merge buffer
  float* Ml = (float*)(smem + 24576);                // [32]
  float* Ll = (float*)(smem + 24576 + 128);          // [32]

  // stage one 64x64 K tile (8KB) into LDS at byte offset koff (linear dest,
  // inverse-swizzled source: physical[row][c16] = logical[row][c16^(row&7)])
  const bf16* kSrcBase = Kp + (size_t)(lane >> 3) * HD + ((lane & 7) ^ (lane >> 3)) * 8;
  auto stageK = [&](int k0, unsigned koff) {
    const bf16* src = kSrcBase + (size_t)k0 * HD;
    bf16* dst = (bf16*)(smem + koff);
#pragma unroll
    for (int i = 0; i < 8; i++)
      gload16(src + i * 8 * HD, dst + i * 512);
  };

  auto run_chunk = [&](int qbase, int nt) {
    // Q frags (B-operand): lane: Q[qbase+q31][ds*16 + hi*8 + e], scaled
    bf16x8 qb[4];
#pragma unroll
    for (int ds = 0; ds < 4; ds++) {
      bf16x8 xq = *(const bf16x8*)(Qp + (size_t)(qbase + q31) * HD + ds * 16 + hi * 8);
#pragma unroll
      for (int e = 0; e < 8; e++) xq[e] = (bf16)((float)xq[e] * SCL);
      qb[ds] = xq;
    }
    float m_r = -3.0e38f, lsum = 0.f;
    f32x16 o0, o1;
#pragma unroll
    for (int e = 0; e < 16; e++) { o0[e] = 0.f; o1[e] = 0.f; }

    unsigned cur = 0;
    if (w < nt) stageK(w * 64, wbase);
    for (int tv = w; tv < nt; tv += 2) {
      const int k0 = tv * 64;
      asm volatile("s_waitcnt vmcnt(0)" ::: "memory");
      __builtin_amdgcn_sched_barrier(0);
      // ---- K frags from LDS (swizzled read), QK^T (swapped: A=K, B=Q) ----
      f32x16 s0, s1;
#pragma unroll
      for (int e = 0; e < 16; e++) { s0[e] = 0.f; s1[e] = 0.f; }
      {
        const unsigned rowb0 = wbase + cur * 8192 + (unsigned)q31 * 128;
        const unsigned sw = (unsigned)(q31 & 7) << 4;
#pragma unroll
        for (int ds = 0; ds < 4; ds++) {
          const unsigned co = (((unsigned)(ds * 2 + hi)) << 4) ^ sw;
          bf16x8 kf0 = *(const bf16x8*)(smem + rowb0 + co);
          bf16x8 kf1 = *(const bf16x8*)(smem + rowb0 + 4096 + co);
          s0 = mfma32(kf0, qb[ds], s0);
          s1 = mfma32(kf1, qb[ds], s1);
        }
      }
      // ---- V frags: pre-fragmented, one contiguous 1KB load each ----
      bf16x8 vf[2][4];
      {
        const bf16* vt = VFp + (size_t)(k0 >> 6) * 4096;   // 2*4*64*8 bf16/tile
#pragma unroll
        for (int dt = 0; dt < 2; dt++)
#pragma unroll
          for (int ks = 0; ks < 4; ks++)
            vf[dt][ks] = *(const bf16x8*)(vt + (size_t)((dt * 4 + ks) * 64 + lane) * 8);
      }
      // ---- prefetch my next tile (tv+2) into other buffer ----
      if (tv + 2 < nt) stageK((tv + 2) * 64, wbase + (cur ^ 1) * 8192);
      // ---- causal mask (diagonal tiles only) ----
      if (k0 + 63 > qbase) {
        const int qg = qbase + q31;
#pragma unroll
        for (int r = 0; r < 16; r++) {
          const int kg = k0 + (r & 3) + 8 * (r >> 2) + 4 * hi;
          if (kg > qg)      s0[r] = -1.0e30f;
          if (kg + 32 > qg) s1[r] = -1.0e30f;
        }
      }
      // ---- in-lane online softmax (exp2 domain), tree reductions, defer-max ----
      {
        float a[16];
#pragma unroll
        for (int r = 0; r < 16; r++) a[r] = fmaxf(s0[r], s1[r]);
#pragma unroll
        for (int d = 8; d > 0; d >>= 1)
#pragma unroll
          for (int r = 0; r < d; r++) a[r] = fmaxf(a[r], a[r + d]);
        const float pm = fmaxf(a[0], __shfl_xor(a[0], 32));
        if (__any(pm > m_r + 8.0f)) {            // T13 defer-max, THR=8
          const float mnew = fmaxf(m_r, pm);
          const float alpha = __builtin_exp2f(m_r - mnew);
          lsum *= alpha;
#pragma unroll
          for (int e = 0; e < 16; e++) { o0[e] *= alpha; o1[e] *= alpha; }
          m_r = mnew;
        }
        float b[16];
#pragma unroll
        for (int r = 0; r < 16; r++) {
          s0[r] = __builtin_exp2f(s0[r] - m_r);
          s1[r] = __builtin_exp2f(s1[r] - m_r);
          b[r] = s0[r] + s1[r];
        }
#pragma unroll
        for (int d = 8; d > 0; d >>= 1)
#pragma unroll
          for (int r = 0; r < d; r++) b[r] += b[r + d];
        lsum += b[0] + __shfl_xor(b[0], 32);
      }
      // ---- pack P into B-frags (16 pack2 + 8 shfl_xor(32)) ----
      bf16x8 pf[4];
#pragma unroll
      for (int ks = 0; ks < 4; ks++) {
        const int rb = 8 * (ks & 1);
        float va0, va1, va2, va3, vb0, vb1, vb2, vb3;
        if (ks < 2) {
          va0 = s0[rb]; va1 = s0[rb + 1]; va2 = s0[rb + 2]; va3 = s0[rb + 3];
          vb0 = s0[rb + 4]; vb1 = s0[rb + 5]; vb2 = s0[rb + 6]; vb3 = s0[rb + 7];
        } else {
          va0 = s1[rb]; va1 = s1[rb + 1]; va2 = s1[rb + 2]; va3 = s1[rb + 3];
          vb0 = s1[rb + 4]; vb1 = s1[rb + 5]; vb2 = s1[rb + 6]; vb3 = s1[rb + 7];
        }
        const unsigned a01 = pack2(va0, va1), a23 = pack2(va2, va3);
        const unsigned b01 = pack2(vb0, vb1), b23 = pack2(vb2, vb3);
        const unsigned z1 = (unsigned)__shfl_xor((int)(hi ? a01 : b01), 32);
        const unsigned z2 = (unsigned)__shfl_xor((int)(hi ? a23 : b23), 32);
        union { unsigned u[4]; bf16x8 v; } cv;
        cv.u[0] = hi ? z1 : a01;
        cv.u[1] = hi ? z2 : a23;
        cv.u[2] = hi ? b01 : z1;
        cv.u[3] = hi ? b23 : z2;
        pf[ks] = cv.v;
      }
      // ---- PV (swapped: A=V, B=P) -> O'[d][q], col=q in-lane ----
#pragma unroll
      for (int ks = 0; ks < 4; ks++) {
        o0 = mfma32(vf[0][ks], pf[ks], o0);
        o1 = mfma32(vf[1][ks], pf[ks], o1);
      }
      cur ^= 1;
    }
    // ---- merge the two wave partials and store ----
    __syncthreads();   // wave1's staging region is dead; safe to reuse as merge buf
    if (w) {
#pragma unroll
      for (int e = 0; e < 16; e++) {
        const int r = (e & 3) + 8 * (e >> 2) + 4 * hi;
        Om[r * 32 + q31] = o0[e];
        Om[(r + 32) * 32 + q31] = o1[e];
      }
      if (!hi) { Ml[q31] = m_r; Ll[q31] = lsum; }
    }
    __syncthreads();
    if (!w) {
      const float m1 = Ml[q31], l1 = Ll[q31];
      const float mm = fmaxf(m_r, m1);
      const float a0 = __builtin_exp2f(m_r - mm);
      const float a1 = __builtin_exp2f(m1 - mm);
      const float linv = 1.0f / (a0 * lsum + a1 * l1);
      const int b = bh >> 4, h = bh & 15;
      const size_t rowb = ((size_t)(b * SS + qbase + q31)) * DM + h * HD;
#pragma unroll
      for (int g2 = 0; g2 < 4; g2++) {
        bf16x4 w0v, w1v;
#pragma unroll
        for (int j = 0; j < 4; j++) {
          const int e = 4 * g2 + j;
          const int r = j + 8 * g2 + 4 * hi;
          w0v[j] = (bf16)((a0 * o0[e] + a1 * Om[r * 32 + q31]) * linv);
          w1v[j] = (bf16)((a0 * o1[e] + a1 * Om[(r + 32) * 32 + q31]) * linv);
        }
        *(bf16x4*)(AO + rowb +      8 * g2 + 4 * hi) = w0v;
        *(bf16x4*)(AO + rowb + 32 + 8 * g2 + 4 * hi) = w1v;
      }
    }
    __syncthreads();   // protect merge buffer before next chunk's staging reuse
  };

  // pair p & 63-p: 33 tiles total per block, uniform across all blocks
  run_chunk(p * 32, p / 2 + 1);
  const int ph = 63 - p;
  run_chunk(ph * 32, ph / 2 + 1);
}

// ---------------- output projection -> fp32 d_out ----------------
__global__ __launch_bounds__(256, 2) void oproj_kernel(const bf16* __restrict__ AO,
    const bf16* __restrict__ wob, float* __restrict__ out) {
  f32x4 acc[4][4];
  const int rowA0 = blockIdx.y * 128, rowB0 = blockIdx.x * 128;
  gemm_bt_128(AO, wob, rowA0, rowB0, acc);
  const int t = threadIdx.x, w = t >> 6, lane = t & 63;
  const int wr = w >> 1, wc = w & 1, g = lane >> 4, c = lane & 15;
#pragma unroll
  for (int mi = 0; mi < 4; mi++)
#pragma unroll
    for (int ni = 0; ni < 4; ni++) {
      const int ncol = rowB0 + wc * 64 + ni * 16 + c;
#pragma unroll
      for (int j = 0; j < 4; j++) {
        const int mrow = rowA0 + wr * 64 + mi * 16 + 4 * g + j;
        out[(size_t)mrow * DM + ncol] = acc[mi][ni][j];
      }
    }
}

extern "C" void kernel_launch(void* const* d_in, const int* in_sizes, int n_in,
                              void* d_out, int out_size, void* d_ws, size_t ws_size,
                              hipStream_t stream) {
  const float* x  = (const float*)d_in[0];
  const float* wq = (const float*)d_in[1];
  const float* wk = (const float*)d_in[2];
  const float* wv = (const float*)d_in[3];
  const float* wo = (const float*)d_in[4];
  const int*   pos = (const int*)d_in[5];
  char* ws = (char*)d_ws;
  bf16* xb   = (bf16*)(ws + OFF_XB);
  bf16* wqkv = (bf16*)(ws + OFF_WQKV);
  bf16* wob  = (bf16*)(ws + OFF_WO);
  fx2*  tab  = (fx2*)(ws + OFF_TAB);
  bf16* Qb   = (bf16*)(ws + OFF_Q);
  bf16* Kb   = (bf16*)(ws + OFF_K);
  bf16* VFb  = (bf16*)(ws + OFF_VF);
  bf16* AOb  = (bf16*)(ws + OFF_AO);

  hipLaunchKernelGGL(prep_kernel, dim3(2048), dim3(256), 0, stream,
                     x, wq, wk, wv, wo, pos, xb, wqkv, wob, tab);
  hipLaunchKernelGGL(qkv_kernel, dim3(24, 32), dim3(256), 0, stream,
                     xb, wqkv, tab, Qb, Kb, VFb);
  hipLaunchKernelGGL(attn_kernel, dim3(1024), dim3(128), 0, stream,
                     Qb, Kb, VFb, AOb);
  hipLaunchKernelGGL(oproj_kernel, dim3(8, 32), dim3(256), 0, stream,
                     AOb, wob, (float*)d_out);
}